// Round 4
// baseline (284.433 us; speedup 1.0000x reference)
//
#include <hip/hip_runtime.h>
#include <math.h>

namespace {

constexpr int L   = 200;
constexpr int E   = 64;
constexpr int H1N = 80;
constexpr int H2N = 40;

using short8 = __attribute__((ext_vector_type(8))) short;
using f32x4  = __attribute__((ext_vector_type(4))) float;

__device__ inline unsigned short f2bf(float f) {
    union { float f; unsigned u; } x{f};
    unsigned r = x.u + 0x7fffu + ((x.u >> 16) & 1u);   // RNE
    return (unsigned short)(r >> 16);
}

// DPP row_ror add: x += ror_n(x) within each 16-lane row (VALU pipe, no LDS)
#define ROR_ADD(x, CTRL) do {                                                   \
    int _t = __builtin_amdgcn_update_dpp(0, __builtin_bit_cast(int, (x)),       \
                                         (CTRL), 0xf, 0xf, true);               \
    (x) += __builtin_bit_cast(float, _t); } while (0)

// ---- workspace layout (bytes) ----
// [0,     20480)  Abf  bf16[1280*8]  GEMM1 B-frags: K=128 (k | k*q), N=80
// [20480, 29696)  W2f  bf16[576*8]   GEMM2 B-frags
// [29696, ...  )  cq_all f32 [B][80]
constexpr int WS_ABF = 0;
constexpr int WS_W2F = 20480;
constexpr int WS_CQ  = 29696;

// One prep kernel: frag packing + cq GEMV, id-partitioned.
__global__ void k0_prep(const float* __restrict__ W1,
                        const float* __restrict__ W2,
                        const float* __restrict__ q,
                        const float* __restrict__ b1,
                        unsigned short* __restrict__ Abf,
                        unsigned short* __restrict__ W2f,
                        float* __restrict__ cq_all, int B)
{
    const int id = blockIdx.x * 256 + threadIdx.x;
    if (id < 1280) {
        // GEMM1 B-frag: frag index u=(nt*4+ks)*64+lane; ks 0,1 -> A=(W1_k-W1_d),
        // ks 2,3 -> C=W1_p (i-halves 0/32). lane(16g+c): j=nt*16+c, i0=(ks&1)*32+g*8
        const int u  = id, cc = u >> 6, ln = u & 63;
        const int nt = cc >> 2, ks = cc & 3;
        const int j  = nt * 16 + (ln & 15);
        const int i0 = (ks & 1) * 32 + (ln >> 4) * 8;
        #pragma unroll
        for (int e = 0; e < 8; ++e) {
            const int i = i0 + e;
            const float v = (ks < 2)
                ? (W1[(E + i) * H1N + j] - W1[(2 * E + i) * H1N + j])
                : W1[(3 * E + i) * H1N + j];
            Abf[u * 8 + e] = f2bf(v);
        }
    } else if (id < 1856) {
        const int u   = id - 1280, cc = u >> 6, ln = u & 63;
        const int nt2 = cc / 3, ks2 = cc % 3;
        const int n   = nt2 * 16 + (ln & 15);
        const int j0  = ks2 * 32 + (ln >> 4) * 8;
        #pragma unroll
        for (int e = 0; e < 8; ++e) {
            const int j = j0 + e;
            W2f[u * 8 + e] = (j < H1N && n < H2N) ? f2bf(W2[j * H2N + n])
                                                  : (unsigned short)0;
        }
    } else {
        // cq[b][jq..jq+4) = b1 + q_b @ (W1_q + W1_d); thread per (b, j-quad)
        const int t = id - 1856;
        if (t >= B * 20) return;
        const int b  = t / 20;
        const int jq = (t - b * 20) * 4;
        const float* qb = q + (size_t)b * E;
        float4 a = *(const float4*)(b1 + jq);
        #pragma unroll 8
        for (int i = 0; i < E; ++i) {
            const float qv = qb[i];
            const float4 wa = *(const float4*)(W1 + i * H1N + jq);
            const float4 wb = *(const float4*)(W1 + (2 * E + i) * H1N + jq);
            a.x += qv * (wa.x + wb.x);
            a.y += qv * (wa.y + wb.y);
            a.z += qv * (wa.z + wb.z);
            a.w += qv * (wa.w + wb.w);
        }
        *(float4*)(cq_all + (size_t)b * H1N + jq) = a;
    }
}

__global__ __launch_bounds__(256, 4)
void attn_main(const float* __restrict__ q,
               const float* __restrict__ kmat,
               const float* __restrict__ vmat,
               const void* __restrict__ mask,
               const float* __restrict__ b2,
               const float* __restrict__ Wf,
               const float* __restrict__ bfp,
               const unsigned short* __restrict__ AbfG,
               const unsigned short* __restrict__ W2fG,
               const float* __restrict__ cq_all,
               float* __restrict__ out, int B)
{
    const int tid  = threadIdx.x;
    const int lane = tid & 63;
    const int wv   = tid >> 6;
    const int g    = lane >> 4;
    const int c    = lane & 15;

    __shared__ short8 Mt[1280];                  // 20480 B: GEMM1 B-frags
    __shared__ unsigned short H1t[4][16][104];   // 13312 B: per-wave H1 tile
    __shared__ float score[4][256];              //  4096 B: per-wave logits/probs
    __shared__ int   flag_s;

    // ---- one-time block staging (the ONLY barrier) ----
    const short8* Ag = (const short8*)AbfG;
    #pragma unroll
    for (int u = 0; u < 5; ++u) Mt[tid + 256 * u] = Ag[tid + 256 * u];
    if (tid == 0) {
        const unsigned char* mb = (const unsigned char*)mask;
        int isI32 = 1;
        for (int t = 0; t < 256; ++t)
            if ((t & 3) && mb[t]) { isI32 = 0; break; }
        flag_s = isI32;
    }
    // zero H1t K-pad cols 80..95 (per-wave, written once)
    *(unsigned long long*)&H1t[wv][c][80 + g * 4] = 0ULL;
    __syncthreads();

    const int bb = blockIdx.x * 4 + wv;          // one batch per wave
    if (bb >= B) return;

    // ---- per-batch setup ----
    const float* qb = q + (size_t)bb * E;
    float qv[2][8];
    #pragma unroll
    for (int kh = 0; kh < 2; ++kh) {
        const float4 t0 = *(const float4*)(qb + kh * 32 + g * 8);
        const float4 t1 = *(const float4*)(qb + kh * 32 + g * 8 + 4);
        qv[kh][0] = t0.x; qv[kh][1] = t0.y; qv[kh][2] = t0.z; qv[kh][3] = t0.w;
        qv[kh][4] = t1.x; qv[kh][5] = t1.y; qv[kh][6] = t1.z; qv[kh][7] = t1.w;
    }
    float cqr[5];
    #pragma unroll
    for (int nt = 0; nt < 5; ++nt)
        cqr[nt] = cq_all[(size_t)bb * H1N + nt * 16 + c];
    float b2r[3], wfr[3];
    #pragma unroll
    for (int nt2 = 0; nt2 < 3; ++nt2) {
        const int nc = nt2 * 16 + c;
        b2r[nt2] = (nc < H2N) ? b2[nc] : 0.f;
        wfr[nt2] = (nc < H2N) ? Wf[nc] : 0.f;
    }
    const float bf0 = bfp[0];
    const short8* W2v = (const short8*)W2fG;

    // ---- MLP: 7 passes x 2 tiles of 16 rows (rows >=200 clamped, masked later) ----
    for (int p = 0; p < 7; ++p) {
        const int r0 = p * 32;
        const float* kp0 = kmat + ((size_t)bb * L + min(r0 + c, L - 1)) * E;
        const float* kp1 = kmat + ((size_t)bb * L + min(r0 + 16 + c, L - 1)) * E;

        f32x4 acc1[2][5];
        #pragma unroll
        for (int tt = 0; tt < 2; ++tt)
            #pragma unroll
            for (int nt = 0; nt < 5; ++nt) acc1[tt][nt] = f32x4{0.f, 0.f, 0.f, 0.f};

        #pragma unroll
        for (int kh = 0; kh < 2; ++kh) {
            const float4 u0 = *(const float4*)(kp0 + kh * 32 + g * 8);
            const float4 u1 = *(const float4*)(kp0 + kh * 32 + g * 8 + 4);
            const float4 w0 = *(const float4*)(kp1 + kh * 32 + g * 8);
            const float4 w1 = *(const float4*)(kp1 + kh * 32 + g * 8 + 4);
            short8 ak0, aq0, ak1, aq1;
            ak0[0] = f2bf(u0.x); ak0[1] = f2bf(u0.y); ak0[2] = f2bf(u0.z); ak0[3] = f2bf(u0.w);
            ak0[4] = f2bf(u1.x); ak0[5] = f2bf(u1.y); ak0[6] = f2bf(u1.z); ak0[7] = f2bf(u1.w);
            aq0[0] = f2bf(u0.x * qv[kh][0]); aq0[1] = f2bf(u0.y * qv[kh][1]);
            aq0[2] = f2bf(u0.z * qv[kh][2]); aq0[3] = f2bf(u0.w * qv[kh][3]);
            aq0[4] = f2bf(u1.x * qv[kh][4]); aq0[5] = f2bf(u1.y * qv[kh][5]);
            aq0[6] = f2bf(u1.z * qv[kh][6]); aq0[7] = f2bf(u1.w * qv[kh][7]);
            ak1[0] = f2bf(w0.x); ak1[1] = f2bf(w0.y); ak1[2] = f2bf(w0.z); ak1[3] = f2bf(w0.w);
            ak1[4] = f2bf(w1.x); ak1[5] = f2bf(w1.y); ak1[6] = f2bf(w1.z); ak1[7] = f2bf(w1.w);
            aq1[0] = f2bf(w0.x * qv[kh][0]); aq1[1] = f2bf(w0.y * qv[kh][1]);
            aq1[2] = f2bf(w0.z * qv[kh][2]); aq1[3] = f2bf(w0.w * qv[kh][3]);
            aq1[4] = f2bf(w1.x * qv[kh][4]); aq1[5] = f2bf(w1.y * qv[kh][5]);
            aq1[6] = f2bf(w1.z * qv[kh][6]); aq1[7] = f2bf(w1.w * qv[kh][7]);
            #pragma unroll
            for (int nt = 0; nt < 5; ++nt) {
                const short8 bk = Mt[(nt * 4 + kh) * 64 + lane];
                const short8 bq = Mt[(nt * 4 + 2 + kh) * 64 + lane];
                acc1[0][nt] = __builtin_amdgcn_mfma_f32_16x16x32_bf16(ak0, bk, acc1[0][nt], 0, 0, 0);
                acc1[0][nt] = __builtin_amdgcn_mfma_f32_16x16x32_bf16(aq0, bq, acc1[0][nt], 0, 0, 0);
                acc1[1][nt] = __builtin_amdgcn_mfma_f32_16x16x32_bf16(ak1, bk, acc1[1][nt], 0, 0, 0);
                acc1[1][nt] = __builtin_amdgcn_mfma_f32_16x16x32_bf16(aq1, bq, acc1[1][nt], 0, 0, 0);
            }
        }

        // GEMM2 + sigmoid + logit per tile (wave-local H1 round-trip)
        auto tile_tail = [&](const f32x4 (&a1)[5], int t) {
            #pragma unroll
            for (int nt = 0; nt < 5; ++nt)
                #pragma unroll
                for (int r = 0; r < 4; ++r)
                    H1t[wv][4 * g + r][nt * 16 + c] = f2bf(a1[nt][r] + cqr[nt]);

            f32x4 acc2[3];
            #pragma unroll
            for (int nt2 = 0; nt2 < 3; ++nt2) acc2[nt2] = f32x4{0.f, 0.f, 0.f, 0.f};
            #pragma unroll
            for (int ks2 = 0; ks2 < 3; ++ks2) {
                const short8 a2 = *(const short8*)&H1t[wv][c][ks2 * 32 + g * 8];
                #pragma unroll
                for (int nt2 = 0; nt2 < 3; ++nt2) {
                    const short8 bw = W2v[(nt2 * 3 + ks2) * 64 + lane];
                    acc2[nt2] = __builtin_amdgcn_mfma_f32_16x16x32_bf16(a2, bw, acc2[nt2], 0, 0, 0);
                }
            }
            float pl[4] = {0.f, 0.f, 0.f, 0.f};
            #pragma unroll
            for (int nt2 = 0; nt2 < 3; ++nt2)
                #pragma unroll
                for (int r = 0; r < 4; ++r) {
                    const float h2 = acc2[nt2][r] + b2r[nt2];
                    const float s  = __builtin_amdgcn_rcpf(1.f + __expf(-h2));
                    pl[r] += s * wfr[nt2];
                }
            // 16-lane sum via DPP rotations (VALU pipe)
            #pragma unroll
            for (int r = 0; r < 4; ++r) {
                ROR_ADD(pl[r], 0x128);
                ROR_ADD(pl[r], 0x124);
                ROR_ADD(pl[r], 0x122);
                ROR_ADD(pl[r], 0x121);
            }
            const float myv = (c == 0) ? pl[0] : (c == 1) ? pl[1] : (c == 2) ? pl[2] : pl[3];
            if (c < 4) score[wv][16 * t + 4 * g + c] = bf0 + myv;
        };
        tile_tail(acc1[0], 2 * p);
        tile_tail(acc1[1], 2 * p + 1);
    }

    // ---- wave-local masked softmax over L ----
    const int l0 = lane * 4;
    const float4 s4 = *(const float4*)&score[wv][l0];
    float lg[4] = {-INFINITY, -INFINITY, -INFINITY, -INFINITY};
    if (l0 < L) {   // lanes 0..49 cover rows 0..199 exactly; mask reads stay in-bounds
        if (flag_s) {
            const int4 m4 = *(const int4*)((const int*)mask + (size_t)bb * L + l0);
            lg[0] = m4.x ? -INFINITY : s4.x;
            lg[1] = m4.y ? -INFINITY : s4.y;
            lg[2] = m4.z ? -INFINITY : s4.z;
            lg[3] = m4.w ? -INFINITY : s4.w;
        } else {
            const unsigned mb = *(const unsigned*)((const unsigned char*)mask + (size_t)bb * L + l0);
            lg[0] = (mb & 0x000000ffu) ? -INFINITY : s4.x;
            lg[1] = (mb & 0x0000ff00u) ? -INFINITY : s4.y;
            lg[2] = (mb & 0x00ff0000u) ? -INFINITY : s4.z;
            lg[3] = (mb & 0xff000000u) ? -INFINITY : s4.w;
        }
    }
    float m = fmaxf(fmaxf(lg[0], lg[1]), fmaxf(lg[2], lg[3]));
    #pragma unroll
    for (int off = 32; off > 0; off >>= 1)
        m = fmaxf(m, __shfl_xor(m, off));
    float ex0 = __expf(lg[0] - m), ex1 = __expf(lg[1] - m);
    float ex2 = __expf(lg[2] - m), ex3 = __expf(lg[3] - m);
    float es = ((ex0 + ex1) + (ex2 + ex3));
    #pragma unroll
    for (int off = 32; off > 0; off >>= 1)
        es += __shfl_xor(es, off);
    *(float4*)&score[wv][l0] = make_float4(ex0, ex1, ex2, ex3);
    const float inv = 1.0f / es;

    // ---- PV: lane(16g+c) accumulates e=[4c,4c+4) over rows 4*ll+g ----
    f32x4 oa = f32x4{0.f, 0.f, 0.f, 0.f};
    const float* vb = vmat + (size_t)bb * L * E;
    #pragma unroll 5
    for (int ll = 0; ll < 50; ++ll) {
        const int row = ll * 4 + g;
        const float sv = score[wv][row];
        const float4 v4 = *(const float4*)(vb + row * E + c * 4);
        oa[0] += sv * v4.x; oa[1] += sv * v4.y;
        oa[2] += sv * v4.z; oa[3] += sv * v4.w;
    }
    #pragma unroll
    for (int j = 0; j < 4; ++j) {
        oa[j] += __shfl_xor(oa[j], 16);
        oa[j] += __shfl_xor(oa[j], 32);
    }
    if (g == 0) {
        float4 o;
        o.x = oa[0] * inv; o.y = oa[1] * inv; o.z = oa[2] * inv; o.w = oa[3] * inv;
        *(float4*)(out + (size_t)bb * E + c * 4) = o;
    }
}

} // namespace

extern "C" void kernel_launch(void* const* d_in, const int* in_sizes, int n_in,
                              void* d_out, int out_size, void* d_ws, size_t ws_size,
                              hipStream_t stream) {
    const float* q  = (const float*)d_in[0];
    const float* k  = (const float*)d_in[1];
    const float* v  = (const float*)d_in[2];
    const void*  mk = d_in[3];
    const float* W1 = (const float*)d_in[4];
    const float* b1 = (const float*)d_in[5];
    const float* W2 = (const float*)d_in[6];
    const float* b2 = (const float*)d_in[7];
    const float* Wf = (const float*)d_in[8];
    const float* bf = (const float*)d_in[9];
    float* out = (float*)d_out;

    const int B = in_sizes[0] / E;   // 4096

    char* ws = (char*)d_ws;
    unsigned short* Abf    = (unsigned short*)(ws + WS_ABF);
    unsigned short* W2f    = (unsigned short*)(ws + WS_W2F);
    float*          cq_all = (float*)(ws + WS_CQ);

    const int prep_ids = 1856 + B * 20;
    k0_prep<<<(prep_ids + 255) / 256, 256, 0, stream>>>(W1, W2, q, b1, Abf, W2f, cq_all, B);
    attn_main<<<(B + 3) / 4, 256, 0, stream>>>(q, k, v, mk, b2, Wf, bf,
                                               Abf, W2f, cq_all, out, B);
}

// Round 5
// 222.344 us; speedup vs baseline: 1.2792x; 1.2792x over previous
//
#include <hip/hip_runtime.h>
#include <math.h>

namespace {

constexpr int L   = 200;
constexpr int E   = 64;
constexpr int H1N = 80;
constexpr int H2N = 40;

using short8 = __attribute__((ext_vector_type(8))) short;
using f32x4  = __attribute__((ext_vector_type(4))) float;

__device__ inline unsigned short f2bf(float f) {
    union { float f; unsigned u; } x{f};
    unsigned r = x.u + 0x7fffu + ((x.u >> 16) & 1u);   // RNE
    return (unsigned short)(r >> 16);
}
__device__ inline float bf2f(short s) {
    union { unsigned u; float f; } x;
    x.u = ((unsigned)(unsigned short)s) << 16;
    return x.f;
}

// DPP row_ror add: x += ror_n(x) within each 16-lane row (VALU pipe, no LDS)
#define ROR_ADD(x, CTRL) do {                                                   \
    int _t = __builtin_amdgcn_update_dpp(0, __builtin_bit_cast(int, (x)),       \
                                         (CTRL), 0xf, 0xf, true);               \
    (x) += __builtin_bit_cast(float, _t); } while (0)

// ---- workspace layout (bytes) ----
constexpr int WS_ABF = 0;        // bf16[1280*8] GEMM1 B-frags (K=128: A | C)
constexpr int WS_W2F = 20480;    // bf16[576*8]  GEMM2 B-frags
constexpr int WS_CQ  = 29696;    // f32 [B][80]  cq

// Prep: frag packing + cq GEMV, id-partitioned.
__global__ void k0_prep(const float* __restrict__ W1,
                        const float* __restrict__ W2,
                        const float* __restrict__ q,
                        const float* __restrict__ b1,
                        unsigned short* __restrict__ Abf,
                        unsigned short* __restrict__ W2f,
                        float* __restrict__ cq_all, int B)
{
    const int id = blockIdx.x * 256 + threadIdx.x;
    if (id < 1280) {
        // frag u=(nt*4+ks)*64+lane; ks 0,1 -> A=(W1_k-W1_d); ks 2,3 -> C=W1_p
        const int u  = id, cc = u >> 6, ln = u & 63;
        const int nt = cc >> 2, ks = cc & 3;
        const int j  = nt * 16 + (ln & 15);
        const int i0 = (ks & 1) * 32 + (ln >> 4) * 8;
        #pragma unroll
        for (int e = 0; e < 8; ++e) {
            const int i = i0 + e;
            const float v = (ks < 2)
                ? (W1[(E + i) * H1N + j] - W1[(2 * E + i) * H1N + j])
                : W1[(3 * E + i) * H1N + j];
            Abf[u * 8 + e] = f2bf(v);
        }
    } else if (id < 1856) {
        const int u   = id - 1280, cc = u >> 6, ln = u & 63;
        const int nt2 = cc / 3, ks2 = cc % 3;
        const int n   = nt2 * 16 + (ln & 15);
        const int j0  = ks2 * 32 + (ln >> 4) * 8;
        #pragma unroll
        for (int e = 0; e < 8; ++e) {
            const int j = j0 + e;
            W2f[u * 8 + e] = (j < H1N && n < H2N) ? f2bf(W2[j * H2N + n])
                                                  : (unsigned short)0;
        }
    } else {
        const int t = id - 1856;
        if (t >= B * 20) return;
        const int b  = t / 20;
        const int jq = (t - b * 20) * 4;
        const float* qb = q + (size_t)b * E;
        float4 a = *(const float4*)(b1 + jq);
        #pragma unroll 8
        for (int i = 0; i < E; ++i) {
            const float qv = qb[i];
            const float4 wa = *(const float4*)(W1 + i * H1N + jq);
            const float4 wb = *(const float4*)(W1 + (2 * E + i) * H1N + jq);
            a.x += qv * (wa.x + wb.x);
            a.y += qv * (wa.y + wb.y);
            a.z += qv * (wa.z + wb.z);
            a.w += qv * (wa.w + wb.w);
        }
        *(float4*)(cq_all + (size_t)b * H1N + jq) = a;
    }
}

// build ak (bf16 of K) and aq (bf16 of K*q) fragments from two float4 + packed q
#define MK_FRAGS(AK, AQ, A0, A1, KH)                                              \
    do {                                                                          \
        AK[0] = (short)f2bf(A0.x); AK[1] = (short)f2bf(A0.y);                     \
        AK[2] = (short)f2bf(A0.z); AK[3] = (short)f2bf(A0.w);                     \
        AK[4] = (short)f2bf(A1.x); AK[5] = (short)f2bf(A1.y);                     \
        AK[6] = (short)f2bf(A1.z); AK[7] = (short)f2bf(A1.w);                     \
        AQ[0] = (short)f2bf(A0.x * bf2f(qbf[KH][0]));                             \
        AQ[1] = (short)f2bf(A0.y * bf2f(qbf[KH][1]));                             \
        AQ[2] = (short)f2bf(A0.z * bf2f(qbf[KH][2]));                             \
        AQ[3] = (short)f2bf(A0.w * bf2f(qbf[KH][3]));                             \
        AQ[4] = (short)f2bf(A1.x * bf2f(qbf[KH][4]));                             \
        AQ[5] = (short)f2bf(A1.y * bf2f(qbf[KH][5]));                             \
        AQ[6] = (short)f2bf(A1.z * bf2f(qbf[KH][6]));                             \
        AQ[7] = (short)f2bf(A1.w * bf2f(qbf[KH][7]));                             \
    } while (0)

__global__ __launch_bounds__(256, 4)
void attn_main(const float* __restrict__ q,
               const float* __restrict__ kmat,
               const float* __restrict__ vmat,
               const void* __restrict__ mask,
               const float* __restrict__ b2,
               const float* __restrict__ Wf,
               const float* __restrict__ bfp,
               const unsigned short* __restrict__ AbfG,
               const unsigned short* __restrict__ W2fG,
               const float* __restrict__ cq_all,
               float* __restrict__ out, int B)
{
    const int tid  = threadIdx.x;
    const int lane = tid & 63;
    const int wv   = tid >> 6;
    const int g    = lane >> 4;
    const int c    = lane & 15;

    __shared__ short8 Mt[1280];                  // 20480 B
    __shared__ unsigned short H1t[4][16][104];   // 13312 B
    __shared__ float score[4][256];              //  4096 B
    __shared__ int   flag_s;

    const int bb = blockIdx.x * 4 + wv;          // one batch per wave
    const int bok = (bb < B);

    // ---- staging (overlaps with per-batch setup loads below) ----
    const short8* Ag = (const short8*)AbfG;
    #pragma unroll
    for (int u = 0; u < 5; ++u) Mt[tid + 256 * u] = Ag[tid + 256 * u];
    if (tid == 0) {
        const unsigned char* mb = (const unsigned char*)mask;
        int isI32 = 1;
        for (int t = 0; t < 256; ++t)
            if ((t & 3) && mb[t]) { isI32 = 0; break; }
        flag_s = isI32;
    }
    *(unsigned long long*)&H1t[wv][c][80 + g * 4] = 0ULL;   // K-pad cols 80..95

    // ---- per-batch setup (before barrier: independent of LDS) ----
    short8 qbf[2] = {short8{0,0,0,0,0,0,0,0}, short8{0,0,0,0,0,0,0,0}};
    float cqr[5] = {0.f,0.f,0.f,0.f,0.f};
    float b2r[3] = {0.f,0.f,0.f}, wfr[3] = {0.f,0.f,0.f};
    float4 kb0{}, kb1{}, kb2{}, kb3{};
    const float* kbase = kmat + (size_t)(bok ? bb : 0) * L * E;
    if (bok) {
        const float* qb = q + (size_t)bb * E;
        #pragma unroll
        for (int kh = 0; kh < 2; ++kh) {
            const float4 t0 = *(const float4*)(qb + kh * 32 + g * 8);
            const float4 t1 = *(const float4*)(qb + kh * 32 + g * 8 + 4);
            short8 p;
            p[0] = (short)f2bf(t0.x); p[1] = (short)f2bf(t0.y);
            p[2] = (short)f2bf(t0.z); p[3] = (short)f2bf(t0.w);
            p[4] = (short)f2bf(t1.x); p[5] = (short)f2bf(t1.y);
            p[6] = (short)f2bf(t1.z); p[7] = (short)f2bf(t1.w);
            qbf[kh] = p;
        }
        #pragma unroll
        for (int nt = 0; nt < 5; ++nt)
            cqr[nt] = cq_all[(size_t)bb * H1N + nt * 16 + c];
        #pragma unroll
        for (int nt2 = 0; nt2 < 3; ++nt2) {
            const int nc = nt2 * 16 + c;
            b2r[nt2] = (nc < H2N) ? b2[nc] : 0.f;
            wfr[nt2] = (nc < H2N) ? Wf[nc] : 0.f;
        }
        // tile 0 k data
        const float* kp = kbase + (size_t)min(c, L - 1) * E;
        kb0 = ((const float4*)kp)[2 * g];
        kb1 = ((const float4*)kp)[2 * g + 1];
        kb2 = ((const float4*)kp)[8 + 2 * g];
        kb3 = ((const float4*)kp)[8 + 2 * g + 1];
    }
    const float bf0 = bfp[0];
    __syncthreads();
    if (!bok) return;

    const short8* W2v = (const short8*)W2fG;   // 9.2 KB, L1-resident

    // ---- 13 tiles of 16 rows, 1 tile/iter, prefetch next ----
    for (int t = 0; t < 13; ++t) {
        short8 ak0, aq0, ak1, aq1;
        MK_FRAGS(ak0, aq0, kb0, kb1, 0);
        MK_FRAGS(ak1, aq1, kb2, kb3, 1);

        if (t < 12) {   // prefetch tile t+1 (latency hides under MFMA + tail)
            const float* kp = kbase + (size_t)min(16 * (t + 1) + c, L - 1) * E;
            kb0 = ((const float4*)kp)[2 * g];
            kb1 = ((const float4*)kp)[2 * g + 1];
            kb2 = ((const float4*)kp)[8 + 2 * g];
            kb3 = ((const float4*)kp)[8 + 2 * g + 1];
        }

        f32x4 acc1[5];
        #pragma unroll
        for (int nt = 0; nt < 5; ++nt) acc1[nt] = f32x4{0.f, 0.f, 0.f, 0.f};
        #pragma unroll
        for (int nt = 0; nt < 5; ++nt) {
            acc1[nt] = __builtin_amdgcn_mfma_f32_16x16x32_bf16(ak0, Mt[(nt * 4 + 0) * 64 + lane], acc1[nt], 0, 0, 0);
            acc1[nt] = __builtin_amdgcn_mfma_f32_16x16x32_bf16(aq0, Mt[(nt * 4 + 2) * 64 + lane], acc1[nt], 0, 0, 0);
            acc1[nt] = __builtin_amdgcn_mfma_f32_16x16x32_bf16(ak1, Mt[(nt * 4 + 1) * 64 + lane], acc1[nt], 0, 0, 0);
            acc1[nt] = __builtin_amdgcn_mfma_f32_16x16x32_bf16(aq1, Mt[(nt * 4 + 3) * 64 + lane], acc1[nt], 0, 0, 0);
        }

        // H1 -> per-wave LDS tile (bf16), then GEMM2
        #pragma unroll
        for (int nt = 0; nt < 5; ++nt)
            #pragma unroll
            for (int r = 0; r < 4; ++r)
                H1t[wv][4 * g + r][nt * 16 + c] = f2bf(acc1[nt][r] + cqr[nt]);

        f32x4 acc2[3];
        #pragma unroll
        for (int nt2 = 0; nt2 < 3; ++nt2) acc2[nt2] = f32x4{0.f, 0.f, 0.f, 0.f};
        #pragma unroll
        for (int ks2 = 0; ks2 < 3; ++ks2) {
            const short8 a2 = *(const short8*)&H1t[wv][c][ks2 * 32 + g * 8];
            #pragma unroll
            for (int nt2 = 0; nt2 < 3; ++nt2)
                acc2[nt2] = __builtin_amdgcn_mfma_f32_16x16x32_bf16(a2, W2v[(nt2 * 3 + ks2) * 64 + lane], acc2[nt2], 0, 0, 0);
        }

        float pl0 = 0.f, pl1 = 0.f, pl2 = 0.f, pl3 = 0.f;
        #pragma unroll
        for (int nt2 = 0; nt2 < 3; ++nt2) {
            const float wfv = wfr[nt2], b2v = b2r[nt2];
            pl0 += wfv * __builtin_amdgcn_rcpf(1.f + __expf(-(acc2[nt2][0] + b2v)));
            pl1 += wfv * __builtin_amdgcn_rcpf(1.f + __expf(-(acc2[nt2][1] + b2v)));
            pl2 += wfv * __builtin_amdgcn_rcpf(1.f + __expf(-(acc2[nt2][2] + b2v)));
            pl3 += wfv * __builtin_amdgcn_rcpf(1.f + __expf(-(acc2[nt2][3] + b2v)));
        }
        ROR_ADD(pl0, 0x128); ROR_ADD(pl0, 0x124); ROR_ADD(pl0, 0x122); ROR_ADD(pl0, 0x121);
        ROR_ADD(pl1, 0x128); ROR_ADD(pl1, 0x124); ROR_ADD(pl1, 0x122); ROR_ADD(pl1, 0x121);
        ROR_ADD(pl2, 0x128); ROR_ADD(pl2, 0x124); ROR_ADD(pl2, 0x122); ROR_ADD(pl2, 0x121);
        ROR_ADD(pl3, 0x128); ROR_ADD(pl3, 0x124); ROR_ADD(pl3, 0x122); ROR_ADD(pl3, 0x121);
        const float myv = (c == 0) ? pl0 : (c == 1) ? pl1 : (c == 2) ? pl2 : pl3;
        if (c < 4) score[wv][16 * t + 4 * g + c] = bf0 + myv;
    }

    // ---- wave-local masked softmax over L ----
    const int l0 = lane * 4;
    const float4 s4 = *(const float4*)&score[wv][l0 < L ? l0 : 0];
    float lg0 = -INFINITY, lg1 = -INFINITY, lg2 = -INFINITY, lg3 = -INFINITY;
    if (l0 < L) {
        if (flag_s) {
            const int4 m4 = *(const int4*)((const int*)mask + (size_t)bb * L + l0);
            lg0 = m4.x ? -INFINITY : s4.x;
            lg1 = m4.y ? -INFINITY : s4.y;
            lg2 = m4.z ? -INFINITY : s4.z;
            lg3 = m4.w ? -INFINITY : s4.w;
        } else {
            const unsigned mb = *(const unsigned*)((const unsigned char*)mask + (size_t)bb * L + l0);
            lg0 = (mb & 0x000000ffu) ? -INFINITY : s4.x;
            lg1 = (mb & 0x0000ff00u) ? -INFINITY : s4.y;
            lg2 = (mb & 0x00ff0000u) ? -INFINITY : s4.z;
            lg3 = (mb & 0xff000000u) ? -INFINITY : s4.w;
        }
    }
    float m = fmaxf(fmaxf(lg0, lg1), fmaxf(lg2, lg3));
    #pragma unroll
    for (int off = 32; off > 0; off >>= 1)
        m = fmaxf(m, __shfl_xor(m, off));
    const float ex0 = __expf(lg0 - m), ex1 = __expf(lg1 - m);
    const float ex2 = __expf(lg2 - m), ex3 = __expf(lg3 - m);
    float es = ((ex0 + ex1) + (ex2 + ex3));
    #pragma unroll
    for (int off = 32; off > 0; off >>= 1)
        es += __shfl_xor(es, off);
    *(float4*)&score[wv][l0] = make_float4(ex0, ex1, ex2, ex3);
    const float inv = 1.0f / es;

    // ---- PV: lane(16g+c) accumulates e=[4c,4c+4) over rows 4*ll+g ----
    f32x4 oa = f32x4{0.f, 0.f, 0.f, 0.f};
    const float* vb = vmat + (size_t)bb * L * E;
    #pragma unroll 10
    for (int ll = 0; ll < 50; ++ll) {
        const int row = ll * 4 + g;
        const float sv = score[wv][row];
        const float4 v4 = *(const float4*)(vb + row * E + c * 4);
        oa[0] += sv * v4.x; oa[1] += sv * v4.y;
        oa[2] += sv * v4.z; oa[3] += sv * v4.w;
    }
    #pragma unroll
    for (int j = 0; j < 4; ++j) {
        oa[j] += __shfl_xor(oa[j], 16);
        oa[j] += __shfl_xor(oa[j], 32);
    }
    if (g == 0) {
        float4 o;
        o.x = oa[0] * inv; o.y = oa[1] * inv; o.z = oa[2] * inv; o.w = oa[3] * inv;
        *(float4*)(out + (size_t)bb * E + c * 4) = o;
    }
}

} // namespace

extern "C" void kernel_launch(void* const* d_in, const int* in_sizes, int n_in,
                              void* d_out, int out_size, void* d_ws, size_t ws_size,
                              hipStream_t stream) {
    const float* q  = (const float*)d_in[0];
    const float* k  = (const float*)d_in[1];
    const float* v  = (const float*)d_in[2];
    const void*  mk = d_in[3];
    const float* W1 = (const float*)d_in[4];
    const float* b1 = (const float*)d_in[5];
    const float* W2 = (const float*)d_in[6];
    const float* b2 = (const float*)d_in[7];
    const float* Wf = (const float*)d_in[8];
    const float* bf = (const float*)d_in[9];
    float* out = (float*)d_out;

    const int B = in_sizes[0] / E;   // 4096

    char* ws = (char*)d_ws;
    unsigned short* Abf    = (unsigned short*)(ws + WS_ABF);
    unsigned short* W2f    = (unsigned short*)(ws + WS_W2F);
    float*          cq_all = (float*)(ws + WS_CQ);

    const int prep_ids = 1856 + B * 20;
    k0_prep<<<(prep_ids + 255) / 256, 256, 0, stream>>>(W1, W2, q, b1, Abf, W2f, cq_all, B);
    attn_main<<<(B + 3) / 4, 256, 0, stream>>>(q, k, v, mk, b2, Wf, bf,
                                               Abf, W2f, cq_all, out, B);
}